// Round 4
// baseline (1063.124 us; speedup 1.0000x reference)
//
#include <hip/hip_runtime.h>
#include <hip/hip_bf16.h>

#define IN_DIM 128
#define OUT_DIM 64
#define RPB 256           // rows per bucket
#define MAXB 400          // max buckets (n_nodes <= 102400)
#define STAGE_CAP 16      // LDS staging capacity per bucket (entries)
#define FLUSH_G 8         // flush granularity: 8 entries = 64B
#define EPB 4096          // edges per k_bin/k_bcount block

__device__ __forceinline__ float wave_sum(float v) {
  v += __shfl_xor(v, 32, 64);
  v += __shfl_xor(v, 16, 64);
  v += __shfl_xor(v, 8, 64);
  v += __shfl_xor(v, 4, 64);
  v += __shfl_xor(v, 2, 64);
  v += __shfl_xor(v, 1, 64);
  return v;
}

// Phase 1: wh = h @ w_w + w_b ; s_row = wh@a1 ; s_col = wh@a2
__global__ __launch_bounds__(256) void k_wh(
    const float* __restrict__ h, const float* __restrict__ w_w,
    const float* __restrict__ w_b, const float* __restrict__ a_w,
    float* __restrict__ wh, float* __restrict__ s_row,
    float* __restrict__ s_col, int n_nodes) {
  __shared__ float sw[IN_DIM * OUT_DIM];
  {
    const float4* src = (const float4*)w_w;
    float4* dst = (float4*)sw;
    for (int i = threadIdx.x; i < IN_DIM * OUT_DIM / 4; i += 256) dst[i] = src[i];
  }
  __syncthreads();
  const int lane = threadIdx.x & 63;
  const int wave = __builtin_amdgcn_readfirstlane(threadIdx.x >> 6);
  const int nbase = blockIdx.x * 16 + wave * 4;
  if (nbase >= n_nodes) return;
  const float* hrow = h + (size_t)nbase * IN_DIM;  // wave-uniform -> scalar loads
  float acc0 = 0.f, acc1 = 0.f, acc2 = 0.f, acc3 = 0.f;
#pragma unroll 16
  for (int k = 0; k < IN_DIM; ++k) {
    float wv = sw[k * OUT_DIM + lane];
    acc0 = fmaf(hrow[k], wv, acc0);
    acc1 = fmaf(hrow[IN_DIM + k], wv, acc1);
    acc2 = fmaf(hrow[2 * IN_DIM + k], wv, acc2);
    acc3 = fmaf(hrow[3 * IN_DIM + k], wv, acc3);
  }
  float bias = w_b[lane];
  float a1 = a_w[lane], a2 = a_w[OUT_DIM + lane];
  acc0 += bias; acc1 += bias; acc2 += bias; acc3 += bias;
  wh[(size_t)(nbase + 0) * OUT_DIM + lane] = acc0;
  wh[(size_t)(nbase + 1) * OUT_DIM + lane] = acc1;
  wh[(size_t)(nbase + 2) * OUT_DIM + lane] = acc2;
  wh[(size_t)(nbase + 3) * OUT_DIM + lane] = acc3;
  float r0 = wave_sum(acc0 * a1), c0 = wave_sum(acc0 * a2);
  float r1 = wave_sum(acc1 * a1), c1 = wave_sum(acc1 * a2);
  float r2 = wave_sum(acc2 * a1), c2 = wave_sum(acc2 * a2);
  float r3 = wave_sum(acc3 * a1), c3 = wave_sum(acc3 * a2);
  if (lane == 0) {
    s_row[nbase + 0] = r0; s_row[nbase + 1] = r1;
    s_row[nbase + 2] = r2; s_row[nbase + 3] = r3;
    s_col[nbase + 0] = c0; s_col[nbase + 1] = c1;
    s_col[nbase + 2] = c2; s_col[nbase + 3] = c3;
  }
}

// Bucket histogram: LDS-local, one global atomic per bucket per block.
__global__ __launch_bounds__(256) void k_bcount(
    const int* __restrict__ ei, int* __restrict__ bucket_cnt, int nedges) {
  __shared__ int hist[MAXB];
  for (int b = threadIdx.x; b < MAXB; b += 256) hist[b] = 0;
  __syncthreads();
  int start = blockIdx.x * EPB;
  int end = min(nedges, start + EPB);
  for (int e = start + threadIdx.x; e < end; e += 256)
    atomicAdd(&hist[ei[e] >> 8], 1);
  __syncthreads();
  for (int b = threadIdx.x; b < MAXB; b += 256)
    if (hist[b]) atomicAdd(&bucket_cnt[b], hist[b]);
}

// Single-block exclusive scan of 128B-padded bucket counts; seeds cursors.
__global__ __launch_bounds__(512) void k_scanB(
    const int* __restrict__ bucket_cnt, int* __restrict__ bucket_off,
    int* __restrict__ cursor, int nb) {
  __shared__ int sd[512];
  int t = threadIdx.x;
  int pc = (t < nb) ? ((bucket_cnt[t] + 15) & ~15) : 0;  // pad to 16 entries=128B
  sd[t] = pc;
  __syncthreads();
  for (int off = 1; off < 512; off <<= 1) {
    int v = (t >= off) ? sd[t - off] : 0;
    __syncthreads();
    sd[t] += v;
    __syncthreads();
  }
  if (t < nb) {
    int ex = sd[t] - pc;
    bucket_off[t] = ex;
    cursor[t] = ex;
  }
}

// Phase 2: stream edges, compute alpha, bin (rowoff<<17|col, alpha) into
// per-bucket LDS staging; flush 64B chunks via ticket atomics with
// wave-cooperative coalesced copies. Scattered stores: 1.6M -> ~200K x 64B.
__global__ __launch_bounds__(256) void k_bin(
    const int* __restrict__ ei, const float* __restrict__ edge_attr,
    const float* __restrict__ a_w, const float* __restrict__ a_b,
    const float* __restrict__ s_row, const float* __restrict__ s_col,
    int* __restrict__ cursor, int2* __restrict__ entries, int nedges) {
  __shared__ int2 stage[MAXB][STAGE_CAP];
  __shared__ int bcnt[MAXB];
  __shared__ int flist[MAXB];
  __shared__ int ftick[MAXB];
  __shared__ int fcnt[MAXB];
  __shared__ int fnum;
  const int tid = threadIdx.x;
  const int lane = tid & 63, wave = tid >> 6;
  for (int b = tid; b < MAXB; b += 256) bcnt[b] = 0;

  // hoist attention coefficients (uniform)
  float aw0 = a_w[128], aw1 = a_w[129], aw2 = a_w[130], aw3 = a_w[131];
  float aw4 = a_w[132], aw5 = a_w[133], aw6 = a_w[134], aw7 = a_w[135];
  float ab = a_b[0];
  __syncthreads();

  const int e0 = blockIdx.x * EPB;
  for (int r = 0; r < EPB / 256; ++r) {
    int e = e0 + r * 256 + tid;
    if (e < nedges) {
      int row = ei[e];
      int col = ei[nedges + e];
      const float4* ea = (const float4*)(edge_attr + (size_t)e * 8);
      float4 u = ea[0], v = ea[1];
      float s = s_row[row] + s_col[col] + ab;
      s += u.x * aw0 + u.y * aw1 + u.z * aw2 + u.w * aw3;
      s += v.x * aw4 + v.y * aw5 + v.z * aw6 + v.w * aw7;
      float ev = (s > 0.f) ? s : 0.01f * s;  // leaky_relu
      float alpha = __expf(ev);               // softmax shift-invariance: no max
      int b = row >> 8;
      int2 entry = make_int2(((row & 255) << 17) | col, __float_as_int(alpha));
      int pos = atomicAdd(&bcnt[b], 1);
      if (pos < STAGE_CAP) {
        stage[b][pos] = entry;
      } else {  // rare spill (needs ~>16 same-bucket hits in one round)
        entries[atomicAdd(&cursor[b], 1)] = entry;
      }
    }
    __syncthreads();
    if (tid == 0) fnum = 0;
    __syncthreads();
    for (int b = tid; b < MAXB; b += 256) {
      if (bcnt[b] >= FLUSH_G) {
        int slot = atomicAdd(&fnum, 1);
        flist[slot] = b;
        ftick[slot] = atomicAdd(&cursor[b], FLUSH_G);
      }
    }
    __syncthreads();
    {
      int nf = fnum;
      for (int base = wave * 8; base < nf; base += 32) {
        int item = base + (lane >> 3);
        if (item < nf && item < base + 8) {
          entries[ftick[item] + (lane & 7)] = stage[flist[item]][lane & 7];
        }
      }
    }
    __syncthreads();
    for (int b = tid; b < MAXB; b += 256) {
      int c = bcnt[b];
      if (c >= FLUSH_G) {
        int cc = min(c, STAGE_CAP);  // beyond-cap entries were spilled directly
        for (int k = FLUSH_G; k < cc; ++k) stage[b][k - FLUSH_G] = stage[b][k];
        bcnt[b] = cc - FLUSH_G;
      }
    }
    __syncthreads();
  }
  // final drain of partial buffers (< FLUSH_G entries each)
  if (tid == 0) fnum = 0;
  __syncthreads();
  for (int b = tid; b < MAXB; b += 256) {
    int c = min(bcnt[b], STAGE_CAP);
    if (c > 0) {
      int slot = atomicAdd(&fnum, 1);
      flist[slot] = b;
      fcnt[slot] = c;
      ftick[slot] = atomicAdd(&cursor[b], c);
    }
  }
  __syncthreads();
  {
    int nf = fnum;
    for (int base = wave * 8; base < nf; base += 32) {
      int item = base + (lane >> 3);
      if (item < nf && item < base + 8) {
        if ((lane & 7) < fcnt[item])
          entries[ftick[item] + (lane & 7)] = stage[flist[item]][lane & 7];
      }
    }
  }
}

// Phase 3: one block per bucket; LDS accumulators (256 rows x 64 dims).
// Stream entries coalesced, broadcast, gather wh[col] 256B coalesced,
// ds_add into LDS; coalesced divide+store epilogue.
__global__ __launch_bounds__(256) void k_agg2(
    const int* __restrict__ bucket_off, const int* __restrict__ bucket_cnt,
    const int2* __restrict__ entries, const float* __restrict__ wh,
    float* __restrict__ out, int n_nodes) {
  __shared__ float acc[RPB * OUT_DIM];  // 64 KB
  __shared__ float nrm[RPB];
  const int b = blockIdx.x;
  const int row0 = b * RPB;
  const int nrows = min(RPB, n_nodes - row0);
  const int tid = threadIdx.x, lane = tid & 63, wave = tid >> 6;
  for (int i = tid; i < RPB * OUT_DIM / 4; i += 256)
    ((float4*)acc)[i] = make_float4(0.f, 0.f, 0.f, 0.f);
  for (int i = tid; i < RPB; i += 256) nrm[i] = 0.f;
  __syncthreads();
  const int start = bucket_off[b];
  const int cnt = bucket_cnt[b];
  for (int base = wave * 64; base < cnt; base += 256) {
    int chunk = min(64, cnt - base);
    int2 p = make_int2(0, 0);
    if (lane < chunk) p = entries[start + base + lane];
    int j = 0;
    for (; j + 4 <= chunk; j += 4) {
      int x0 = __shfl(p.x, j, 64), y0 = __shfl(p.y, j, 64);
      int x1 = __shfl(p.x, j + 1, 64), y1 = __shfl(p.y, j + 1, 64);
      int x2 = __shfl(p.x, j + 2, 64), y2 = __shfl(p.y, j + 2, 64);
      int x3 = __shfl(p.x, j + 3, 64), y3 = __shfl(p.y, j + 3, 64);
      float w0 = wh[(size_t)(x0 & 0x1FFFF) * OUT_DIM + lane];
      float w1 = wh[(size_t)(x1 & 0x1FFFF) * OUT_DIM + lane];
      float w2 = wh[(size_t)(x2 & 0x1FFFF) * OUT_DIM + lane];
      float w3 = wh[(size_t)(x3 & 0x1FFFF) * OUT_DIM + lane];
      atomicAdd(&acc[((x0 >> 17) << 6) + lane], __int_as_float(y0) * w0);
      atomicAdd(&acc[((x1 >> 17) << 6) + lane], __int_as_float(y1) * w1);
      atomicAdd(&acc[((x2 >> 17) << 6) + lane], __int_as_float(y2) * w2);
      atomicAdd(&acc[((x3 >> 17) << 6) + lane], __int_as_float(y3) * w3);
      if (lane == 0) atomicAdd(&nrm[x0 >> 17], __int_as_float(y0));
      if (lane == 1) atomicAdd(&nrm[x1 >> 17], __int_as_float(y1));
      if (lane == 2) atomicAdd(&nrm[x2 >> 17], __int_as_float(y2));
      if (lane == 3) atomicAdd(&nrm[x3 >> 17], __int_as_float(y3));
    }
    for (; j < chunk; ++j) {
      int x = __shfl(p.x, j, 64), y = __shfl(p.y, j, 64);
      float w = wh[(size_t)(x & 0x1FFFF) * OUT_DIM + lane];
      atomicAdd(&acc[((x >> 17) << 6) + lane], __int_as_float(y) * w);
      if (lane == 0) atomicAdd(&nrm[x >> 17], __int_as_float(y));
    }
  }
  __syncthreads();
  for (int r = wave; r < nrows; r += 4)
    out[(size_t)(row0 + r) * OUT_DIM + lane] = acc[(r << 6) + lane] / (nrm[r] + 1e-8f);
}

extern "C" void kernel_launch(void* const* d_in, const int* in_sizes, int n_in,
                              void* d_out, int out_size, void* d_ws, size_t ws_size,
                              hipStream_t stream) {
  const float* h         = (const float*)d_in[0];
  const int*   ei        = (const int*)d_in[1];
  const float* edge_attr = (const float*)d_in[2];
  const float* w_w       = (const float*)d_in[3];
  const float* w_b       = (const float*)d_in[4];
  const float* a_w       = (const float*)d_in[5];
  const float* a_b       = (const float*)d_in[6];
  const int n_nodes = in_sizes[0] / IN_DIM;
  const int nedges  = in_sizes[1] / 2;
  const int nb = (n_nodes + RPB - 1) / RPB;          // 391 for 100k
  const int nebl = (nedges + EPB - 1) / EPB;         // 391 for 1.6M

  // Workspace layout. entries first (128B-aligned bucket regions).
  int2*  entries    = (int2*)d_ws;                             // nedges + MAXB*16
  float* wh         = (float*)(entries + nedges + MAXB * 16);  // n*64
  float* s_row      = wh + (size_t)n_nodes * OUT_DIM;          // n
  float* s_col      = s_row + n_nodes;                         // n
  int*   bucket_cnt = (int*)(s_col + n_nodes);                 // MAXB (zeroed)
  int*   bucket_off = bucket_cnt + MAXB;                       // MAXB
  int*   cursor     = bucket_off + MAXB;                       // MAXB

  hipMemsetAsync(bucket_cnt, 0, MAXB * sizeof(int), stream);

  k_bcount<<<nebl, 256, 0, stream>>>(ei, bucket_cnt, nedges);
  k_scanB<<<1, 512, 0, stream>>>(bucket_cnt, bucket_off, cursor, nb);
  k_wh<<<(n_nodes + 15) / 16, 256, 0, stream>>>(h, w_w, w_b, a_w, wh, s_row, s_col, n_nodes);
  k_bin<<<nebl, 256, 0, stream>>>(ei, edge_attr, a_w, a_b, s_row, s_col,
                                  cursor, entries, nedges);
  k_agg2<<<nb, 256, 0, stream>>>(bucket_off, bucket_cnt, entries, wh,
                                 (float*)d_out, n_nodes);
}

// Round 5
// 337.898 us; speedup vs baseline: 3.1463x; 3.1463x over previous
//
#include <hip/hip_runtime.h>
#include <hip/hip_fp16.h>

#define IN_DIM 128
#define OUT_DIM 64
#define RPB 256          // rows per bucket
#define MAXB 400         // max buckets  (n_nodes <= 102400)
#define MAXBL 400        // max edge-blocks (nedges <= 1638400)
#define EPB 4096         // edges per block in k_pre/k_fill

__device__ __forceinline__ float wave_sum(float v) {
  v += __shfl_xor(v, 32, 64);
  v += __shfl_xor(v, 16, 64);
  v += __shfl_xor(v, 8, 64);
  v += __shfl_xor(v, 4, 64);
  v += __shfl_xor(v, 2, 64);
  v += __shfl_xor(v, 1, 64);
  return v;
}

// Phase 1: wh = h @ w_w + w_b (stored fp16); s_row = wh@a1 ; s_col = wh@a2
// (s computed from fp32 accumulators before rounding).
__global__ __launch_bounds__(256) void k_wh(
    const float* __restrict__ h, const float* __restrict__ w_w,
    const float* __restrict__ w_b, const float* __restrict__ a_w,
    __half* __restrict__ wh, float* __restrict__ s_row,
    float* __restrict__ s_col, int n_nodes) {
  __shared__ float sw[IN_DIM * OUT_DIM];
  {
    const float4* src = (const float4*)w_w;
    float4* dst = (float4*)sw;
    for (int i = threadIdx.x; i < IN_DIM * OUT_DIM / 4; i += 256) dst[i] = src[i];
  }
  __syncthreads();
  const int lane = threadIdx.x & 63;
  const int wave = __builtin_amdgcn_readfirstlane(threadIdx.x >> 6);
  const int nbase = blockIdx.x * 16 + wave * 4;
  if (nbase >= n_nodes) return;
  const float* hrow = h + (size_t)nbase * IN_DIM;  // wave-uniform -> scalar loads
  float acc0 = 0.f, acc1 = 0.f, acc2 = 0.f, acc3 = 0.f;
#pragma unroll 16
  for (int k = 0; k < IN_DIM; ++k) {
    float wv = sw[k * OUT_DIM + lane];
    acc0 = fmaf(hrow[k], wv, acc0);
    acc1 = fmaf(hrow[IN_DIM + k], wv, acc1);
    acc2 = fmaf(hrow[2 * IN_DIM + k], wv, acc2);
    acc3 = fmaf(hrow[3 * IN_DIM + k], wv, acc3);
  }
  float bias = w_b[lane];
  float a1 = a_w[lane], a2 = a_w[OUT_DIM + lane];
  acc0 += bias; acc1 += bias; acc2 += bias; acc3 += bias;
  wh[(size_t)(nbase + 0) * OUT_DIM + lane] = __float2half(acc0);
  wh[(size_t)(nbase + 1) * OUT_DIM + lane] = __float2half(acc1);
  wh[(size_t)(nbase + 2) * OUT_DIM + lane] = __float2half(acc2);
  wh[(size_t)(nbase + 3) * OUT_DIM + lane] = __float2half(acc3);
  float r0 = wave_sum(acc0 * a1), c0 = wave_sum(acc0 * a2);
  float r1 = wave_sum(acc1 * a1), c1 = wave_sum(acc1 * a2);
  float r2 = wave_sum(acc2 * a1), c2 = wave_sum(acc2 * a2);
  float r3 = wave_sum(acc3 * a1), c3 = wave_sum(acc3 * a2);
  if (lane == 0) {
    s_row[nbase + 0] = r0; s_row[nbase + 1] = r1;
    s_row[nbase + 2] = r2; s_row[nbase + 3] = r3;
    s_col[nbase + 0] = c0; s_col[nbase + 1] = c1;
    s_col[nbase + 2] = c2; s_col[nbase + 3] = c3;
  }
}

// Per-block bucket histogram (LDS only; one coalesced row write per block).
__global__ __launch_bounds__(256) void k_pre(
    const int* __restrict__ ei, int* __restrict__ blockhist, int nedges) {
  __shared__ int hist[MAXB];
  for (int b = threadIdx.x; b < MAXB; b += 256) hist[b] = 0;
  __syncthreads();
  const int e0 = blockIdx.x * EPB;
#pragma unroll 4
  for (int r = 0; r < EPB / 256; ++r) {
    int e = e0 + r * 256 + threadIdx.x;
    if (e < nedges) atomicAdd(&hist[ei[e] >> 8], 1);
  }
  __syncthreads();
  for (int b = threadIdx.x; b < MAXB; b += 256)
    blockhist[blockIdx.x * MAXB + b] = hist[b];
}

// Per-bucket exclusive scan over blocks: boff[bl][b], cnt[b].
__global__ __launch_bounds__(256) void k_scanA(
    const int* __restrict__ blockhist, int* __restrict__ boff,
    int* __restrict__ cnt, int nbl) {
  __shared__ int sd[256];
  const int b = blockIdx.x, t = threadIdx.x;
  int i0 = 2 * t, i1 = 2 * t + 1;
  int v0 = (i0 < nbl) ? blockhist[i0 * MAXB + b] : 0;
  int v1 = (i1 < nbl) ? blockhist[i1 * MAXB + b] : 0;
  int ts = v0 + v1;
  sd[t] = ts;
  __syncthreads();
  for (int off = 1; off < 256; off <<= 1) {
    int x = (t >= off) ? sd[t - off] : 0;
    __syncthreads();
    sd[t] += x;
    __syncthreads();
  }
  int excl = sd[t] - ts;
  if (i0 < nbl) boff[i0 * MAXB + b] = excl;
  if (i1 < nbl) boff[i1 * MAXB + b] = excl + v0;
  if (t == 255) cnt[b] = sd[255];
}

// Exclusive scan of 128B-padded bucket counts -> bucket bases.
__global__ __launch_bounds__(512) void k_scanB(
    const int* __restrict__ cnt, int* __restrict__ bbase) {
  __shared__ int sd[512];
  int t = threadIdx.x;
  int pc = (t < MAXB) ? ((cnt[t] + 15) & ~15) : 0;  // pad to 16 entries = 128B
  sd[t] = pc;
  __syncthreads();
  for (int off = 1; off < 512; off <<= 1) {
    int x = (t >= off) ? sd[t - off] : 0;
    __syncthreads();
    sd[t] += x;
    __syncthreads();
  }
  if (t < MAXB) bbase[t] = sd[t] - pc;
}

// Phase 2: score -> alpha -> deterministic bucket-grouped fill. Each
// (block,bucket) range is contiguous (avg ~10 entries) -> same-XCD L2 line
// merge -> near-payload write traffic (vs 102MB amp with ticket scatter).
__global__ __launch_bounds__(256) void k_fill(
    const int* __restrict__ ei, const float* __restrict__ edge_attr,
    const float* __restrict__ a_w, const float* __restrict__ a_b,
    const float* __restrict__ s_row, const float* __restrict__ s_col,
    const int* __restrict__ boff, const int* __restrict__ bbase,
    int2* __restrict__ entA, int nedges) {
  __shared__ int cur[MAXB];
  for (int b = threadIdx.x; b < MAXB; b += 256)
    cur[b] = bbase[b] + boff[blockIdx.x * MAXB + b];
  float aw0 = a_w[128], aw1 = a_w[129], aw2 = a_w[130], aw3 = a_w[131];
  float aw4 = a_w[132], aw5 = a_w[133], aw6 = a_w[134], aw7 = a_w[135];
  float ab = a_b[0];
  __syncthreads();
  const int e0 = blockIdx.x * EPB;
  for (int r = 0; r < EPB / 256; ++r) {
    int e = e0 + r * 256 + threadIdx.x;
    if (e < nedges) {
      int row = ei[e];
      int col = ei[nedges + e];
      const float4* ea = (const float4*)(edge_attr + (size_t)e * 8);
      float4 u = ea[0], v = ea[1];
      float s = s_row[row] + s_col[col] + ab;
      s += u.x * aw0 + u.y * aw1 + u.z * aw2 + u.w * aw3;
      s += v.x * aw4 + v.y * aw5 + v.z * aw6 + v.w * aw7;
      float ev = (s > 0.f) ? s : 0.01f * s;  // leaky_relu
      float alpha = __expf(ev);  // softmax shift-invariance: no segment max
      int pos = atomicAdd(&cur[row >> 8], 1);  // LDS cursor, deterministic range
      entA[pos] = make_int2(((row & 255) << 17) | col, __float_as_int(alpha));
    }
  }
}

// Per-bucket counting sort (hist in LDS, entries stay in global -> no
// capacity limit). Emits node-level CSR offsets/counts + row-sorted entries.
__global__ __launch_bounds__(256) void k_sortb(
    const int2* __restrict__ entA, int2* __restrict__ entB,
    const int* __restrict__ cnt, const int* __restrict__ bbase,
    int* __restrict__ nodeoffs, int* __restrict__ nodecnt, int n_nodes) {
  __shared__ int hist[RPB];
  __shared__ int loffs[RPB];
  __shared__ int cur[RPB];
  const int b = blockIdx.x, t = threadIdx.x;
  const int c = cnt[b];
  const int base = bbase[b];
  const int row0 = b << 8;
  hist[t] = 0;
  __syncthreads();
  for (int i = t; i < c; i += 256) atomicAdd(&hist[entA[base + i].x >> 17], 1);
  __syncthreads();
  int hh = hist[t];
  loffs[t] = hh;
  __syncthreads();
  for (int off = 1; off < 256; off <<= 1) {
    int x = (t >= off) ? loffs[t - off] : 0;
    __syncthreads();
    loffs[t] += x;
    __syncthreads();
  }
  int excl = loffs[t] - hh;
  cur[t] = excl;
  int node = row0 + t;
  if (node < n_nodes) {
    nodeoffs[node] = base + excl;
    nodecnt[node] = hh;
  }
  __syncthreads();
  for (int i = t; i < c; i += 256) {
    int2 p = entA[base + i];
    int pos = atomicAdd(&cur[p.x >> 17], 1);
    entB[base + pos] = p;
  }
}

// Phase 3: pull aggregation, quarter-wave layout: 16 lanes x float4 per edge,
// 4 edges/wave in flight x2 unroll. fp16 wh halves gather traffic.
__global__ __launch_bounds__(256) void k_agg(
    const int* __restrict__ nodeoffs, const int* __restrict__ nodecnt,
    const int2* __restrict__ ent, const __half* __restrict__ wh,
    float* __restrict__ out, int n_nodes) {
  int v = blockIdx.x * 4 + (threadIdx.x >> 6);
  if (v >= n_nodes) return;
  const int lane = threadIdx.x & 63;
  const int slot = lane >> 4, sub = lane & 15;
  const int start = __builtin_amdgcn_readfirstlane(nodeoffs[v]);
  const int deg = __builtin_amdgcn_readfirstlane(nodecnt[v]);
  const uint2* whq = (const uint2*)wh;  // 8B = 4 halves per lane
  float4 acc = make_float4(0.f, 0.f, 0.f, 0.f);
  float l = 0.f;
  for (int base = 0; base < deg; base += 8) {
    int i0 = base + slot, i1 = base + 4 + slot;
    if (i0 < deg) {
      int2 p = ent[start + i0];
      float a = __int_as_float(p.y);
      uint2 q = whq[(size_t)(p.x & 0x1FFFF) * 16 + sub];
      float2 f0 = __half22float2(*(__half2*)&q.x);
      float2 f1 = __half22float2(*(__half2*)&q.y);
      acc.x = fmaf(a, f0.x, acc.x); acc.y = fmaf(a, f0.y, acc.y);
      acc.z = fmaf(a, f1.x, acc.z); acc.w = fmaf(a, f1.y, acc.w);
      if (sub == 0) l += a;
    }
    if (i1 < deg) {
      int2 p = ent[start + i1];
      float a = __int_as_float(p.y);
      uint2 q = whq[(size_t)(p.x & 0x1FFFF) * 16 + sub];
      float2 f0 = __half22float2(*(__half2*)&q.x);
      float2 f1 = __half22float2(*(__half2*)&q.y);
      acc.x = fmaf(a, f0.x, acc.x); acc.y = fmaf(a, f0.y, acc.y);
      acc.z = fmaf(a, f1.x, acc.z); acc.w = fmaf(a, f1.y, acc.w);
      if (sub == 0) l += a;
    }
  }
  // reduce the 4 slots (lanes differing in bits 4,5)
  acc.x += __shfl_xor(acc.x, 16, 64); acc.x += __shfl_xor(acc.x, 32, 64);
  acc.y += __shfl_xor(acc.y, 16, 64); acc.y += __shfl_xor(acc.y, 32, 64);
  acc.z += __shfl_xor(acc.z, 16, 64); acc.z += __shfl_xor(acc.z, 32, 64);
  acc.w += __shfl_xor(acc.w, 16, 64); acc.w += __shfl_xor(acc.w, 32, 64);
  l += __shfl_xor(l, 16, 64); l += __shfl_xor(l, 32, 64);
  float lt = __shfl(l, 0, 64);
  if (slot == 0) {
    float inv = 1.0f / (lt + 1e-8f);
    float4 o = make_float4(acc.x * inv, acc.y * inv, acc.z * inv, acc.w * inv);
    ((float4*)out)[(size_t)v * 16 + sub] = o;
  }
}

extern "C" void kernel_launch(void* const* d_in, const int* in_sizes, int n_in,
                              void* d_out, int out_size, void* d_ws, size_t ws_size,
                              hipStream_t stream) {
  const float* h         = (const float*)d_in[0];
  const int*   ei        = (const int*)d_in[1];
  const float* edge_attr = (const float*)d_in[2];
  const float* w_w       = (const float*)d_in[3];
  const float* w_b       = (const float*)d_in[4];
  const float* a_w       = (const float*)d_in[5];
  const float* a_b       = (const float*)d_in[6];
  const int n_nodes = in_sizes[0] / IN_DIM;
  const int nedges  = in_sizes[1] / 2;
  const int nb   = (n_nodes + RPB - 1) / RPB;   // 391
  const int nebl = (nedges + EPB - 1) / EPB;    // 391

  // Workspace (~41 MB):
  __half* wh       = (__half*)d_ws;                          // n*64 fp16
  int2*  entA      = (int2*)(wh + (size_t)n_nodes * OUT_DIM);// nedges + MAXB*16
  int*   blockhist = (int*)(entA + nedges + MAXB * 16);      // MAXBL*MAXB
  int*   boff      = blockhist + MAXB * MAXBL;               // MAXBL*MAXB
  int*   cnt       = boff + MAXB * MAXBL;                    // MAXB
  int*   bbase     = cnt + MAXB;                             // MAXB
  int*   nodeoffs  = bbase + MAXB;                           // n
  int*   nodecnt   = nodeoffs + n_nodes;                     // n
  int2*  entB      = (int2*)(nodecnt + n_nodes);             // nedges + MAXB*16
  // s_row/s_col alias entB's tail-unused space timeline: they die before
  // k_sortb writes entB.
  float* s_row     = (float*)entB;                           // n
  float* s_col     = s_row + n_nodes;                        // n

  k_wh<<<(n_nodes + 15) / 16, 256, 0, stream>>>(h, w_w, w_b, a_w, wh, s_row, s_col,
                                                n_nodes);
  k_pre<<<nebl, 256, 0, stream>>>(ei, blockhist, nedges);
  k_scanA<<<MAXB, 256, 0, stream>>>(blockhist, boff, cnt, nebl);
  k_scanB<<<1, 512, 0, stream>>>(cnt, bbase);
  k_fill<<<nebl, 256, 0, stream>>>(ei, edge_attr, a_w, a_b, s_row, s_col,
                                   boff, bbase, entA, nedges);
  k_sortb<<<nb, 256, 0, stream>>>(entA, entB, cnt, bbase, nodeoffs, nodecnt, n_nodes);
  k_agg<<<(n_nodes + 3) / 4, 256, 0, stream>>>(nodeoffs, nodecnt, entB, wh,
                                               (float*)d_out, n_nodes);
}

// Round 6
// 332.825 us; speedup vs baseline: 3.1942x; 1.0152x over previous
//
#include <hip/hip_runtime.h>
#include <hip/hip_fp16.h>

#define IN_DIM 128
#define OUT_DIM 64
#define RPB 512          // rows per bucket
#define MAXB 200         // max buckets  (n_nodes <= 102400)
#define MAXBL 200        // max edge-blocks (nedges <= 1638400)
#define EPB 8192         // edges per block in k_pre/k_fill (512 thr x 16)

__device__ __forceinline__ float wave_sum(float v) {
  v += __shfl_xor(v, 32, 64);
  v += __shfl_xor(v, 16, 64);
  v += __shfl_xor(v, 8, 64);
  v += __shfl_xor(v, 4, 64);
  v += __shfl_xor(v, 2, 64);
  v += __shfl_xor(v, 1, 64);
  return v;
}

// Phase 1: wh = h @ w_w + w_b (stored fp16); s_row = wh@a1 ; s_col = wh@a2
__global__ __launch_bounds__(256) void k_wh(
    const float* __restrict__ h, const float* __restrict__ w_w,
    const float* __restrict__ w_b, const float* __restrict__ a_w,
    __half* __restrict__ wh, float* __restrict__ s_row,
    float* __restrict__ s_col, int n_nodes) {
  __shared__ float sw[IN_DIM * OUT_DIM];
  {
    const float4* src = (const float4*)w_w;
    float4* dst = (float4*)sw;
    for (int i = threadIdx.x; i < IN_DIM * OUT_DIM / 4; i += 256) dst[i] = src[i];
  }
  __syncthreads();
  const int lane = threadIdx.x & 63;
  const int wave = __builtin_amdgcn_readfirstlane(threadIdx.x >> 6);
  const int nbase = blockIdx.x * 16 + wave * 4;
  if (nbase >= n_nodes) return;
  const float* hrow = h + (size_t)nbase * IN_DIM;  // wave-uniform -> scalar loads
  float acc0 = 0.f, acc1 = 0.f, acc2 = 0.f, acc3 = 0.f;
#pragma unroll 16
  for (int k = 0; k < IN_DIM; ++k) {
    float wv = sw[k * OUT_DIM + lane];
    acc0 = fmaf(hrow[k], wv, acc0);
    acc1 = fmaf(hrow[IN_DIM + k], wv, acc1);
    acc2 = fmaf(hrow[2 * IN_DIM + k], wv, acc2);
    acc3 = fmaf(hrow[3 * IN_DIM + k], wv, acc3);
  }
  float bias = w_b[lane];
  float a1 = a_w[lane], a2 = a_w[OUT_DIM + lane];
  acc0 += bias; acc1 += bias; acc2 += bias; acc3 += bias;
  wh[(size_t)(nbase + 0) * OUT_DIM + lane] = __float2half(acc0);
  wh[(size_t)(nbase + 1) * OUT_DIM + lane] = __float2half(acc1);
  wh[(size_t)(nbase + 2) * OUT_DIM + lane] = __float2half(acc2);
  wh[(size_t)(nbase + 3) * OUT_DIM + lane] = __float2half(acc3);
  float r0 = wave_sum(acc0 * a1), c0 = wave_sum(acc0 * a2);
  float r1 = wave_sum(acc1 * a1), c1 = wave_sum(acc1 * a2);
  float r2 = wave_sum(acc2 * a1), c2 = wave_sum(acc2 * a2);
  float r3 = wave_sum(acc3 * a1), c3 = wave_sum(acc3 * a2);
  if (lane == 0) {
    s_row[nbase + 0] = r0; s_row[nbase + 1] = r1;
    s_row[nbase + 2] = r2; s_row[nbase + 3] = r3;
    s_col[nbase + 0] = c0; s_col[nbase + 1] = c1;
    s_col[nbase + 2] = c2; s_col[nbase + 3] = c3;
  }
}

// Per-block bucket histogram (LDS only; one coalesced row write per block).
__global__ __launch_bounds__(512) void k_pre(
    const int* __restrict__ ei, int* __restrict__ blockhist, int nedges) {
  __shared__ int hist[MAXB];
  for (int b = threadIdx.x; b < MAXB; b += 512) hist[b] = 0;
  __syncthreads();
  const int e0 = blockIdx.x * EPB;
#pragma unroll 4
  for (int r = 0; r < EPB / 512; ++r) {
    int e = e0 + r * 512 + threadIdx.x;
    if (e < nedges) atomicAdd(&hist[ei[e] >> 9], 1);
  }
  __syncthreads();
  for (int b = threadIdx.x; b < MAXB; b += 512)
    blockhist[blockIdx.x * MAXB + b] = hist[b];
}

// Per-bucket exclusive scan over blocks of LINE-PADDED counts (roundup 8
// entries = 64B) -> every (block,bucket) run starts line-aligned, single
// writer per line -> no cross-XCD partial-line writeback amplification.
__global__ __launch_bounds__(256) void k_scanA(
    const int* __restrict__ blockhist, int* __restrict__ boff,
    int* __restrict__ cnt, int nbl) {
  __shared__ int sd[256];
  const int b = blockIdx.x, t = threadIdx.x;
  int i0 = 2 * t, i1 = 2 * t + 1;
  int v0 = (i0 < nbl) ? ((blockhist[i0 * MAXB + b] + 7) & ~7) : 0;
  int v1 = (i1 < nbl) ? ((blockhist[i1 * MAXB + b] + 7) & ~7) : 0;
  int ts = v0 + v1;
  sd[t] = ts;
  __syncthreads();
  for (int off = 1; off < 256; off <<= 1) {
    int x = (t >= off) ? sd[t - off] : 0;
    __syncthreads();
    sd[t] += x;
    __syncthreads();
  }
  int excl = sd[t] - ts;
  if (i0 < nbl) boff[i0 * MAXB + b] = excl;
  if (i1 < nbl) boff[i1 * MAXB + b] = excl + v0;
  if (t == 255) cnt[b] = sd[255];  // padded bucket total (multiple of 8)
}

// Exclusive scan of 128B-padded bucket counts -> bucket bases.
__global__ __launch_bounds__(256) void k_scanB(
    const int* __restrict__ cnt, int* __restrict__ bbase, int nb) {
  __shared__ int sd[256];
  int t = threadIdx.x;
  int pc = (t < nb) ? ((cnt[t] + 15) & ~15) : 0;
  sd[t] = pc;
  __syncthreads();
  for (int off = 1; off < 256; off <<= 1) {
    int x = (t >= off) ? sd[t - off] : 0;
    __syncthreads();
    sd[t] += x;
    __syncthreads();
  }
  if (t < nb) bbase[t] = sd[t] - pc;
}

// Phase 2: score -> alpha -> deterministic line-aligned bucket-grouped fill.
// Run tails padded with x=-1 sentinels (same lines as real entries).
__global__ __launch_bounds__(512) void k_fill(
    const int* __restrict__ ei, const float* __restrict__ edge_attr,
    const float* __restrict__ a_w, const float* __restrict__ a_b,
    const float* __restrict__ s_row, const float* __restrict__ s_col,
    const int* __restrict__ boff, const int* __restrict__ bbase,
    int2* __restrict__ entA, int nedges, int nb) {
  __shared__ int cur[MAXB];
  for (int b = threadIdx.x; b < MAXB; b += 512)
    cur[b] = (b < nb) ? bbase[b] + boff[blockIdx.x * MAXB + b] : 0;
  float aw0 = a_w[128], aw1 = a_w[129], aw2 = a_w[130], aw3 = a_w[131];
  float aw4 = a_w[132], aw5 = a_w[133], aw6 = a_w[134], aw7 = a_w[135];
  float ab = a_b[0];
  __syncthreads();
  const int e0 = blockIdx.x * EPB;
  for (int r = 0; r < EPB / 512; ++r) {
    int e = e0 + r * 512 + threadIdx.x;
    if (e < nedges) {
      int row = ei[e];
      int col = ei[nedges + e];
      const float4* ea = (const float4*)(edge_attr + (size_t)e * 8);
      float4 u = ea[0], v = ea[1];
      float s = s_row[row] + s_col[col] + ab;
      s += u.x * aw0 + u.y * aw1 + u.z * aw2 + u.w * aw3;
      s += v.x * aw4 + v.y * aw5 + v.z * aw6 + v.w * aw7;
      float ev = (s > 0.f) ? s : 0.01f * s;  // leaky_relu
      float alpha = __expf(ev);  // softmax shift-invariance: no segment max
      int pos = atomicAdd(&cur[row >> 9], 1);  // LDS cursor, deterministic run
      entA[pos] = make_int2(((row & 511) << 17) | col, __float_as_int(alpha));
    }
  }
  __syncthreads();
  // pad each run's tail to its 64B line end with sentinels
  for (int b = threadIdx.x; b < nb; b += 512) {
    int c = cur[b], end = (c + 7) & ~7;
    for (int k = c; k < end; ++k) entA[k] = make_int2(-1, 0);
  }
}

// Per-bucket counting sort (hist in LDS, entries in global). Skips
// sentinels. Emits node CSR offsets/counts + row-sorted packed entries.
__global__ __launch_bounds__(512) void k_sortb(
    const int2* __restrict__ entA, int2* __restrict__ entB,
    const int* __restrict__ cnt, const int* __restrict__ bbase,
    int* __restrict__ nodeoffs, int* __restrict__ nodecnt, int n_nodes) {
  __shared__ int hist[RPB];
  __shared__ int loffs[RPB];
  __shared__ int cur[RPB];
  const int b = blockIdx.x, t = threadIdx.x;
  const int c = cnt[b];       // padded count
  const int base = bbase[b];
  const int row0 = b << 9;
  hist[t] = 0;
  __syncthreads();
  for (int i = t; i < c; i += 512) {
    int x = entA[base + i].x;
    if (x >= 0) atomicAdd(&hist[x >> 17], 1);
  }
  __syncthreads();
  int hh = hist[t];
  loffs[t] = hh;
  __syncthreads();
  for (int off = 1; off < 512; off <<= 1) {
    int x = (t >= off) ? loffs[t - off] : 0;
    __syncthreads();
    loffs[t] += x;
    __syncthreads();
  }
  int excl = loffs[t] - hh;
  cur[t] = excl;
  int node = row0 + t;
  if (node < n_nodes) {
    nodeoffs[node] = base + excl;  // entB packed per bucket at padded base
    nodecnt[node] = hh;
  }
  __syncthreads();
  for (int i = t; i < c; i += 512) {
    int2 p = entA[base + i];
    if (p.x >= 0) {
      int pos = atomicAdd(&cur[p.x >> 17], 1);
      entB[base + pos] = p;
    }
  }
}

// Phase 3: pull aggregation, quarter-wave: 16 lanes x 8B fp16 per edge,
// 4 edges/wave in flight x2 unroll.
__global__ __launch_bounds__(256) void k_agg(
    const int* __restrict__ nodeoffs, const int* __restrict__ nodecnt,
    const int2* __restrict__ ent, const __half* __restrict__ wh,
    float* __restrict__ out, int n_nodes) {
  int v = blockIdx.x * 4 + (threadIdx.x >> 6);
  if (v >= n_nodes) return;
  const int lane = threadIdx.x & 63;
  const int slot = lane >> 4, sub = lane & 15;
  const int start = __builtin_amdgcn_readfirstlane(nodeoffs[v]);
  const int deg = __builtin_amdgcn_readfirstlane(nodecnt[v]);
  const uint2* whq = (const uint2*)wh;  // 8B = 4 halves per lane
  float4 acc = make_float4(0.f, 0.f, 0.f, 0.f);
  float l = 0.f;
  for (int base = 0; base < deg; base += 8) {
    int i0 = base + slot, i1 = base + 4 + slot;
    if (i0 < deg) {
      int2 p = ent[start + i0];
      float a = __int_as_float(p.y);
      uint2 q = whq[(size_t)(p.x & 0x1FFFF) * 16 + sub];
      float2 f0 = __half22float2(*(__half2*)&q.x);
      float2 f1 = __half22float2(*(__half2*)&q.y);
      acc.x = fmaf(a, f0.x, acc.x); acc.y = fmaf(a, f0.y, acc.y);
      acc.z = fmaf(a, f1.x, acc.z); acc.w = fmaf(a, f1.y, acc.w);
      if (sub == 0) l += a;
    }
    if (i1 < deg) {
      int2 p = ent[start + i1];
      float a = __int_as_float(p.y);
      uint2 q = whq[(size_t)(p.x & 0x1FFFF) * 16 + sub];
      float2 f0 = __half22float2(*(__half2*)&q.x);
      float2 f1 = __half22float2(*(__half2*)&q.y);
      acc.x = fmaf(a, f0.x, acc.x); acc.y = fmaf(a, f0.y, acc.y);
      acc.z = fmaf(a, f1.x, acc.z); acc.w = fmaf(a, f1.y, acc.w);
      if (sub == 0) l += a;
    }
  }
  acc.x += __shfl_xor(acc.x, 16, 64); acc.x += __shfl_xor(acc.x, 32, 64);
  acc.y += __shfl_xor(acc.y, 16, 64); acc.y += __shfl_xor(acc.y, 32, 64);
  acc.z += __shfl_xor(acc.z, 16, 64); acc.z += __shfl_xor(acc.z, 32, 64);
  acc.w += __shfl_xor(acc.w, 16, 64); acc.w += __shfl_xor(acc.w, 32, 64);
  l += __shfl_xor(l, 16, 64); l += __shfl_xor(l, 32, 64);
  float lt = __shfl(l, 0, 64);
  if (slot == 0) {
    float inv = 1.0f / (lt + 1e-8f);
    float4 o = make_float4(acc.x * inv, acc.y * inv, acc.z * inv, acc.w * inv);
    ((float4*)out)[(size_t)v * 16 + sub] = o;
  }
}

extern "C" void kernel_launch(void* const* d_in, const int* in_sizes, int n_in,
                              void* d_out, int out_size, void* d_ws, size_t ws_size,
                              hipStream_t stream) {
  const float* h         = (const float*)d_in[0];
  const int*   ei        = (const int*)d_in[1];
  const float* edge_attr = (const float*)d_in[2];
  const float* w_w       = (const float*)d_in[3];
  const float* w_b       = (const float*)d_in[4];
  const float* a_w       = (const float*)d_in[5];
  const float* a_b       = (const float*)d_in[6];
  const int n_nodes = in_sizes[0] / IN_DIM;
  const int nedges  = in_sizes[1] / 2;
  const int nb   = (n_nodes + RPB - 1) / RPB;   // 196
  const int nebl = (nedges + EPB - 1) / EPB;    // 196

  // entA capacity with line padding: nedges + nebl*nb*8 + bucket pads
  const size_t entcap = (size_t)nedges + (size_t)MAXBL * MAXB * 8 + MAXB * 16;

  // Workspace (~46 MB; R0 used ~59 MB so ws_size is sufficient):
  __half* wh       = (__half*)d_ws;                           // n*64 fp16
  int2*  entA      = (int2*)(wh + (size_t)n_nodes * OUT_DIM); // entcap
  int*   blockhist = (int*)(entA + entcap);                   // MAXBL*MAXB
  int*   boff      = blockhist + MAXB * MAXBL;                // MAXBL*MAXB
  int*   cnt       = boff + MAXB * MAXBL;                     // MAXB
  int*   bbase     = cnt + MAXB;                              // MAXB
  int*   nodeoffs  = bbase + MAXB;                            // n
  int*   nodecnt   = nodeoffs + n_nodes;                      // n
  int2*  entB      = (int2*)(nodecnt + n_nodes);              // entcap
  // s_row/s_col alias entB (they die before k_sortb writes entB)
  float* s_row     = (float*)entB;                            // n
  float* s_col     = s_row + n_nodes;                         // n

  k_wh<<<(n_nodes + 15) / 16, 256, 0, stream>>>(h, w_w, w_b, a_w, wh, s_row, s_col,
                                                n_nodes);
  k_pre<<<nebl, 512, 0, stream>>>(ei, blockhist, nedges);
  k_scanA<<<nb, 256, 0, stream>>>(blockhist, boff, cnt, nebl);
  k_scanB<<<1, 256, 0, stream>>>(cnt, bbase, nb);
  k_fill<<<nebl, 512, 0, stream>>>(ei, edge_attr, a_w, a_b, s_row, s_col,
                                   boff, bbase, entA, nedges, nb);
  k_sortb<<<nb, 512, 0, stream>>>(entA, entB, cnt, bbase, nodeoffs, nodecnt, n_nodes);
  k_agg<<<(n_nodes + 3) / 4, 256, 0, stream>>>(nodeoffs, nodecnt, entB, wh,
                                               (float*)d_out, n_nodes);
}